// Round 2
// baseline (187.651 us; speedup 1.0000x reference)
//
#include <hip/hip_runtime.h>

typedef __attribute__((ext_vector_type(8))) short short8;
typedef __attribute__((ext_vector_type(4))) float f32x4;
typedef __attribute__((ext_vector_type(4))) unsigned short ushort4_t;
typedef unsigned short ushort_t;

#define D_MODEL 768
#define NHEAD 12
#define HD 64
#define BATCH 4
#define HWIDTH 32
#define HW 1024
#define TOK (BATCH*HW)
#define QKV_N (3*D_MODEL)
#define BH (BATCH*NHEAD)

__device__ __forceinline__ ushort_t f2bf(float f) {
    union { float f; unsigned u; } v; v.f = f;
    unsigned u = v.u;
    unsigned r = u + 0x7FFFu + ((u >> 16) & 1u);
    return (ushort_t)(r >> 16);
}
__device__ __forceinline__ float bf2f(ushort_t h) {
    union { unsigned u; float f; } v; v.u = ((unsigned)h) << 16;
    return v.f;
}
__device__ __forceinline__ int iabs(int x) { return x < 0 ? -x : x; }

// ---------------- RMSNorm: one wave per token ----------------
__global__ void rmsnorm_kernel(const float* __restrict__ x, const float* __restrict__ gamma,
                               ushort_t* __restrict__ xn) {
    int wave = threadIdx.x >> 6, lane = threadIdx.x & 63;
    int t = blockIdx.x * 4 + wave;
    const float* xr = x + (size_t)t * D_MODEL;
    float v[12]; float ss = 0.f;
    #pragma unroll
    for (int j = 0; j < 12; ++j) { v[j] = xr[lane + j*64]; ss += v[j]*v[j]; }
    #pragma unroll
    for (int m = 1; m < 64; m <<= 1) ss += __shfl_xor(ss, m, 64);
    float r = rsqrtf(ss * (1.f/768.f) + 1e-6f);
    ushort_t* o = xn + (size_t)t * D_MODEL;
    #pragma unroll
    for (int j = 0; j < 12; ++j) o[lane + j*64] = f2bf(v[j] * r * gamma[lane + j*64]);
}

// ---------------- f32 -> bf16 convert ----------------
__global__ void cvt_kernel(const float* __restrict__ in, ushort_t* __restrict__ out, int n) {
    int i = blockIdx.x * blockDim.x + threadIdx.x;
    if (i < n) out[i] = f2bf(in[i]);
}

// ---------------- axial RoPE sin/cos tables (1024 x 32) ----------------
__global__ void sincos_kernel(float* __restrict__ sint, float* __restrict__ cost) {
    int i = blockIdx.x * blockDim.x + threadIdx.x; // 32768
    int p = i >> 5, j = i & 31;
    int r = p >> 5, c = p & 31;
    int jj = j & 15;
    float freq = powf(10000.f, -(float)(2*jj) / 32.f);
    float pos = (j < 16) ? (float)r : (float)c;
    float th = pos * freq;
    sint[i] = sinf(th);
    cost[i] = cosf(th);
}

// ---------------- bf16 B^T GEMM: C[M,N] = A[M,K] * B[N,K]^T ----------------
template<typename OutT>
__global__ __launch_bounds__(256) void gemm_bt(const ushort_t* __restrict__ A,
                                               const ushort_t* __restrict__ B,
                                               OutT* __restrict__ C, int M, int N, int K) {
    __shared__ ushort_t As[128*32];
    __shared__ ushort_t Bs[128*32];
    int tn = blockIdx.x * 128, tm = blockIdx.y * 128;
    int w = threadIdx.x >> 6, lane = threadIdx.x & 63;
    int wr = w >> 1, wc = w & 1;
    int l15 = lane & 15, l4 = lane >> 4;
    f32x4 acc[4][4] = {};
    for (int k0 = 0; k0 < K; k0 += 32) {
        #pragma unroll
        for (int is = 0; is < 2; ++is) {
            int c = is*256 + w*64 + lane;
            int row = c >> 2, cc = c & 3;
            const ushort_t* ga = A + (size_t)(tm + row)*K + k0 + cc*8;
            __builtin_amdgcn_global_load_lds((const __attribute__((address_space(1))) void*)ga,
                (__attribute__((address_space(3))) void*)(As + (size_t)(is*256 + w*64)*8), 16, 0, 0);
            const ushort_t* gb = B + (size_t)(tn + row)*K + k0 + cc*8;
            __builtin_amdgcn_global_load_lds((const __attribute__((address_space(1))) void*)gb,
                (__attribute__((address_space(3))) void*)(Bs + (size_t)(is*256 + w*64)*8), 16, 0, 0);
        }
        __syncthreads();
        short8 af[4], bfr[4];
        #pragma unroll
        for (int i = 0; i < 4; ++i)
            af[i] = *(const short8*)&As[(size_t)(wr*64 + i*16 + l15)*32 + l4*8];
        #pragma unroll
        for (int i = 0; i < 4; ++i)
            bfr[i] = *(const short8*)&Bs[(size_t)(wc*64 + i*16 + l15)*32 + l4*8];
        #pragma unroll
        for (int mi = 0; mi < 4; ++mi)
            #pragma unroll
            for (int ni = 0; ni < 4; ++ni)
                acc[mi][ni] = __builtin_amdgcn_mfma_f32_16x16x32_bf16(af[mi], bfr[ni], acc[mi][ni], 0, 0, 0);
        __syncthreads();
    }
    #pragma unroll
    for (int mi = 0; mi < 4; ++mi) {
        #pragma unroll
        for (int ni = 0; ni < 4; ++ni) {
            #pragma unroll
            for (int r = 0; r < 4; ++r) {
                int row = tm + wr*64 + mi*16 + l4*4 + r;
                int col = tn + wc*64 + ni*16 + l15;
                float val = acc[mi][ni][r];
                if constexpr (sizeof(OutT) == 2) C[(size_t)row*N + col] = f2bf(val);
                else                             C[(size_t)row*N + col] = val;
            }
        }
    }
}

// ---------------- RoPE apply + per-head layout for Q, K ----------------
__global__ void rope_kernel(const ushort_t* __restrict__ qkv, const float* __restrict__ sint,
                            const float* __restrict__ cost, ushort_t* __restrict__ Q,
                            ushort_t* __restrict__ Kt) {
    int i = blockIdx.x * blockDim.x + threadIdx.x; // 48*1024*32
    int d = i & 31; int p = (i >> 5) & 1023; int bh = i >> 15;
    int b = bh / NHEAD, h = bh % NHEAD;
    size_t t = (size_t)b * HW + p;
    const ushort_t* row = qkv + t * QKV_N;
    float s = sint[p*32 + d], c = cost[p*32 + d];
    float q0 = bf2f(row[h*64 + d]), q1 = bf2f(row[h*64 + d + 32]);
    float k0 = bf2f(row[768 + h*64 + d]), k1 = bf2f(row[768 + h*64 + d + 32]);
    size_t o = (size_t)bh * HW * HD + (size_t)p * HD + d;
    Q[o]      = f2bf(q0*c - q1*s);
    Q[o + 32] = f2bf(q1*c + q0*s);
    Kt[o]      = f2bf(k0*c - k1*s);
    Kt[o + 32] = f2bf(k1*c + k0*s);
}

// ---------------- V transpose: VT (BH, HD, HW) bf16 ----------------
__global__ void vt_kernel(const ushort_t* __restrict__ qkv, ushort_t* __restrict__ VT) {
    int i = blockIdx.x * blockDim.x + threadIdx.x; // 48*64*1024
    int p = i & 1023; int d = (i >> 10) & 63; int bh = i >> 16;
    int b = bh / NHEAD, h = bh % NHEAD;
    size_t t = (size_t)b * HW + p;
    VT[(size_t)bh * HD * HW + (size_t)d * HW + p] = qkv[t * QKV_N + 1536 + h*64 + d];
}

// ---------------- flash attention, swapped-QK^T layout, kv-split=2 ----------------
// grid (16, 48, 2); block 256 = 4 waves; wave: 16 q-rows, 8 kv-tiles of 64
__global__ __launch_bounds__(256) void attn_kernel(const ushort_t* __restrict__ Q,
                                                   const ushort_t* __restrict__ Kt,
                                                   const ushort_t* __restrict__ VT,
                                                   float* __restrict__ Opart,
                                                   float2* __restrict__ Ml) {
    __shared__ ushort_t P[4][16][72]; // 144B rows: conflict-free b128 reads
    int bh = blockIdx.y;
    int split = blockIdx.z;
    int w = threadIdx.x >> 6, lane = threadIdx.x & 63;
    int l15 = lane & 15, l4 = lane >> 4;
    int qbase = blockIdx.x * 64 + w * 16;
    int q = qbase + l15;
    int qr = q >> 5, qc = q & 31;
    const ushort_t* Qh = Q + (size_t)bh * HW * HD;
    const ushort_t* Kh = Kt + (size_t)bh * HW * HD;
    const ushort_t* Vh = VT + (size_t)bh * HD * HW;
    short8 aq0 = *(const short8*)&Qh[(size_t)(qbase + l15)*64 + l4*8];
    short8 aq1 = *(const short8*)&Qh[(size_t)(qbase + l15)*64 + 32 + l4*8];
    float m = -1e30f, lsum = 0.f;
    f32x4 oacc[4] = {};
    int kv0 = split * 512;

    for (int kv = kv0; kv < kv0 + 512; kv += 64) {
        f32x4 s[4];
        #pragma unroll
        for (int st = 0; st < 4; ++st) {
            int kb = kv + st*16;
            short8 bk0 = *(const short8*)&Kh[(size_t)(kb + l15)*64 + l4*8];
            short8 bk1 = *(const short8*)&Kh[(size_t)(kb + l15)*64 + 32 + l4*8];
            f32x4 z = {};
            z = __builtin_amdgcn_mfma_f32_16x16x32_bf16(bk0, aq0, z, 0, 0, 0); // S^T
            z = __builtin_amdgcn_mfma_f32_16x16x32_bf16(bk1, aq1, z, 0, 0, 0);
            s[st] = z;
        }
        // mask + scale; per-lane single q
        #pragma unroll
        for (int st = 0; st < 4; ++st) {
            #pragma unroll
            for (int i = 0; i < 4; ++i) {
                int k = kv + st*16 + l4*4 + i;
                int kr = k >> 5, kc = k & 31;
                bool excl = (iabs(qr-kr) <= 1) && (iabs(qc-kc) <= 1);
                s[st][i] = excl ? -1e30f : s[st][i] * 0.125f;
            }
        }
        // local max over 16 + 2 shfls across l4 groups
        float vmax = -1e30f;
        #pragma unroll
        for (int st = 0; st < 4; ++st)
            #pragma unroll
            for (int i = 0; i < 4; ++i) vmax = fmaxf(vmax, s[st][i]);
        vmax = fmaxf(vmax, __shfl_xor(vmax, 16, 64));
        vmax = fmaxf(vmax, __shfl_xor(vmax, 32, 64));
        float mn = fmaxf(m, vmax);
        float sf = __expf(m - mn);
        m = mn;
        lsum *= sf;
        #pragma unroll
        for (int dt = 0; dt < 4; ++dt)
            #pragma unroll
            for (int i = 0; i < 4; ++i) oacc[dt][i] *= sf;
        float ls = 0.f;
        #pragma unroll
        for (int st = 0; st < 4; ++st) {
            #pragma unroll
            for (int i = 0; i < 4; ++i) {
                float p = __expf(s[st][i] - mn);
                s[st][i] = p;
                ls += p;
            }
        }
        ls += __shfl_xor(ls, 16, 64);
        ls += __shfl_xor(ls, 32, 64);
        lsum += ls;
        // P store: lane's 4 k-values are contiguous -> one b64 per st
        #pragma unroll
        for (int st = 0; st < 4; ++st) {
            ushort4_t pk;
            pk.x = f2bf(s[st][0]); pk.y = f2bf(s[st][1]);
            pk.z = f2bf(s[st][2]); pk.w = f2bf(s[st][3]);
            *(ushort4_t*)&P[w][l15][st*16 + l4*4] = pk;
        }
        short8 pf0 = *(const short8*)&P[w][l15][l4*8];
        short8 pf1 = *(const short8*)&P[w][l15][32 + l4*8];
        // PV: O^T = V^T * P^T  (A = V^T frag, B = P frag)
        #pragma unroll
        for (int dt = 0; dt < 4; ++dt) {
            short8 va0 = *(const short8*)&Vh[(size_t)(dt*16 + l15)*HW + kv + l4*8];
            short8 va1 = *(const short8*)&Vh[(size_t)(dt*16 + l15)*HW + kv + 32 + l4*8];
            oacc[dt] = __builtin_amdgcn_mfma_f32_16x16x32_bf16(va0, pf0, oacc[dt], 0, 0, 0);
            oacc[dt] = __builtin_amdgcn_mfma_f32_16x16x32_bf16(va1, pf1, oacc[dt], 0, 0, 0);
        }
    }
    // write partials: O rows d contiguous per (dt): f32x4
    size_t rowid = (size_t)(split*BH + bh) * HW + q;
    #pragma unroll
    for (int dt = 0; dt < 4; ++dt)
        *(f32x4*)&Opart[rowid*64 + dt*16 + l4*4] = oacc[dt];
    if (l4 == 0) Ml[rowid] = make_float2(m, lsum);
}

// ---------------- combine two kv-splits ----------------
__global__ void combine_kernel(const float* __restrict__ Opart, const float2* __restrict__ Ml,
                               ushort_t* __restrict__ Ao) {
    int w = threadIdx.x >> 6, lane = threadIdx.x & 63;
    int row = blockIdx.x * 4 + w; // 0..49151
    int bh = row >> 10, q = row & 1023;
    int b = bh / NHEAD, h = bh % NHEAD;
    float2 ml1 = Ml[row];
    float2 ml2 = Ml[(size_t)BH*HW + row];
    float mm = fmaxf(ml1.x, ml2.x);
    float e1 = __expf(ml1.x - mm), e2 = __expf(ml2.x - mm);
    float denom = e1*ml1.y + e2*ml2.y;
    float o1 = Opart[(size_t)row*64 + lane];
    float o2 = Opart[((size_t)BH*HW + row)*64 + lane];
    float o = (e1*o1 + e2*o2) / denom;
    Ao[((size_t)b*HW + q)*D_MODEL + h*64 + lane] = f2bf(o);
}

extern "C" void kernel_launch(void* const* d_in, const int* in_sizes, int n_in,
                              void* d_out, int out_size, void* d_ws, size_t ws_size,
                              hipStream_t stream) {
    const float* x      = (const float*)d_in[0];
    const float* w_qkv  = (const float*)d_in[1];
    const float* w_out  = (const float*)d_in[2];
    const float* gamma  = (const float*)d_in[3];
    float* out = (float*)d_out;

    char* ws = (char*)d_ws;
    size_t off = 0;
    auto alloc = [&](size_t bytes) { char* p = ws + off; off += (bytes + 255) & ~255ull; return p; };
    ushort_t* xn   = (ushort_t*)alloc((size_t)TOK*D_MODEL*2);
    ushort_t* wq   = (ushort_t*)alloc((size_t)QKV_N*D_MODEL*2);
    ushort_t* wo   = (ushort_t*)alloc((size_t)D_MODEL*D_MODEL*2);
    float* sint    = (float*)alloc((size_t)HW*32*4);
    float* cost    = (float*)alloc((size_t)HW*32*4);
    ushort_t* Qr   = (ushort_t*)alloc((size_t)BH*HW*HD*2);
    ushort_t* Kr   = (ushort_t*)alloc((size_t)BH*HW*HD*2);
    ushort_t* VTt  = (ushort_t*)alloc((size_t)BH*HD*HW*2);
    ushort_t* Ao   = (ushort_t*)alloc((size_t)TOK*D_MODEL*2);
    // big region: qkv (dead after rope/vt) aliased with attention partials
    size_t qkv_bytes   = (size_t)TOK*QKV_N*2;                 // 18.9 MB
    size_t opart_bytes = (size_t)2*BH*HW*64*4;                // 25.2 MB
    size_t ml_bytes    = (size_t)2*BH*HW*8;                   // 0.8 MB
    char* big = alloc(opart_bytes + ml_bytes > qkv_bytes ? opart_bytes + ml_bytes : qkv_bytes);
    ushort_t* qkv  = (ushort_t*)big;
    float* Opart   = (float*)big;
    float2* Ml     = (float2*)(big + opart_bytes);

    rmsnorm_kernel<<<TOK/4, 256, 0, stream>>>(x, gamma, xn);
    cvt_kernel<<<(QKV_N*D_MODEL + 255)/256, 256, 0, stream>>>(w_qkv, wq, QKV_N*D_MODEL);
    cvt_kernel<<<(D_MODEL*D_MODEL + 255)/256, 256, 0, stream>>>(w_out, wo, D_MODEL*D_MODEL);
    sincos_kernel<<<HW*32/256, 256, 0, stream>>>(sint, cost);
    gemm_bt<ushort_t><<<dim3(QKV_N/128, TOK/128), 256, 0, stream>>>(xn, wq, qkv, TOK, QKV_N, D_MODEL);
    rope_kernel<<<BH*HW*32/256, 256, 0, stream>>>(qkv, sint, cost, Qr, Kr);
    vt_kernel<<<BH*HD*HW/256, 256, 0, stream>>>(qkv, VTt);
    attn_kernel<<<dim3(HW/64, BH, 2), 256, 0, stream>>>(Qr, Kr, VTt, Opart, Ml);
    combine_kernel<<<BH*HW/4, 256, 0, stream>>>(Opart, Ml, Ao);
    gemm_bt<float><<<dim3(D_MODEL/128, TOK/128), 256, 0, stream>>>(Ao, wo, out, TOK, D_MODEL, D_MODEL);
}

// Round 3
// 187.077 us; speedup vs baseline: 1.0031x; 1.0031x over previous
//
#include <hip/hip_runtime.h>

typedef __attribute__((ext_vector_type(8))) short short8;
typedef __attribute__((ext_vector_type(4))) float f32x4;
typedef unsigned short ushort_t;
typedef unsigned long long u64;

#define D_MODEL 768
#define NHEAD 12
#define HD 64
#define BATCH 4
#define HWIDTH 32
#define HW 1024
#define TOK (BATCH*HW)
#define QKV_N (3*D_MODEL)
#define BH (BATCH*NHEAD)
#define QSCALE 0.18033688f  /* 0.125 * log2(e) */

__device__ __forceinline__ ushort_t f2bf(float f) {
    union { float f; unsigned u; } v; v.f = f;
    unsigned u = v.u;
    unsigned r = u + 0x7FFFu + ((u >> 16) & 1u);
    return (ushort_t)(r >> 16);
}
__device__ __forceinline__ float bf2f(ushort_t h) {
    union { unsigned u; float f; } v; v.u = ((unsigned)h) << 16;
    return v.f;
}
__device__ __forceinline__ float ex2(float x) {
    float r; asm("v_exp_f32 %0, %1" : "=v"(r) : "v"(x)); return r;
}
__device__ __forceinline__ unsigned cvtpk(float lo, float hi) {
    unsigned r; asm("v_cvt_pk_bf16_f32 %0, %1, %2" : "=v"(r) : "v"(lo), "v"(hi)); return r;
}

// ---------------- RMSNorm: one wave per token ----------------
__global__ void rmsnorm_kernel(const float* __restrict__ x, const float* __restrict__ gamma,
                               ushort_t* __restrict__ xn) {
    int wave = threadIdx.x >> 6, lane = threadIdx.x & 63;
    int t = blockIdx.x * 4 + wave;
    const float* xr = x + (size_t)t * D_MODEL;
    float v[12]; float ss = 0.f;
    #pragma unroll
    for (int j = 0; j < 12; ++j) { v[j] = xr[lane + j*64]; ss += v[j]*v[j]; }
    #pragma unroll
    for (int m = 1; m < 64; m <<= 1) ss += __shfl_xor(ss, m, 64);
    float r = rsqrtf(ss * (1.f/768.f) + 1e-6f);
    ushort_t* o = xn + (size_t)t * D_MODEL;
    #pragma unroll
    for (int j = 0; j < 12; ++j) o[lane + j*64] = f2bf(v[j] * r * gamma[lane + j*64]);
}

// ---------------- f32 -> bf16 convert ----------------
__global__ void cvt_kernel(const float* __restrict__ in, ushort_t* __restrict__ out, int n) {
    int i = blockIdx.x * blockDim.x + threadIdx.x;
    if (i < n) out[i] = f2bf(in[i]);
}

// ---------------- axial RoPE sin/cos tables (1024 x 32) ----------------
__global__ void sincos_kernel(float* __restrict__ sint, float* __restrict__ cost) {
    int i = blockIdx.x * blockDim.x + threadIdx.x; // 32768
    int p = i >> 5, j = i & 31;
    int r = p >> 5, c = p & 31;
    int jj = j & 15;
    float freq = powf(10000.f, -(float)(2*jj) / 32.f);
    float pos = (j < 16) ? (float)r : (float)c;
    float th = pos * freq;
    sint[i] = sinf(th);
    cost[i] = cosf(th);
}

// ---------------- bf16 B^T GEMM: C[M,N] = A[M,K] * B[N,K]^T ----------------
template<typename OutT>
__global__ __launch_bounds__(256) void gemm_bt(const ushort_t* __restrict__ A,
                                               const ushort_t* __restrict__ B,
                                               OutT* __restrict__ C, int M, int N, int K) {
    __shared__ ushort_t As[128*32];
    __shared__ ushort_t Bs[128*32];
    int tn = blockIdx.x * 128, tm = blockIdx.y * 128;
    int w = threadIdx.x >> 6, lane = threadIdx.x & 63;
    int wr = w >> 1, wc = w & 1;
    int l15 = lane & 15, l4 = lane >> 4;
    f32x4 acc[4][4] = {};
    for (int k0 = 0; k0 < K; k0 += 32) {
        #pragma unroll
        for (int is = 0; is < 2; ++is) {
            int c = is*256 + w*64 + lane;
            int row = c >> 2, cc = c & 3;
            const ushort_t* ga = A + (size_t)(tm + row)*K + k0 + cc*8;
            __builtin_amdgcn_global_load_lds((const __attribute__((address_space(1))) void*)ga,
                (__attribute__((address_space(3))) void*)(As + (size_t)(is*256 + w*64)*8), 16, 0, 0);
            const ushort_t* gb = B + (size_t)(tn + row)*K + k0 + cc*8;
            __builtin_amdgcn_global_load_lds((const __attribute__((address_space(1))) void*)gb,
                (__attribute__((address_space(3))) void*)(Bs + (size_t)(is*256 + w*64)*8), 16, 0, 0);
        }
        __syncthreads();
        short8 af[4], bfr[4];
        #pragma unroll
        for (int i = 0; i < 4; ++i)
            af[i] = *(const short8*)&As[(size_t)(wr*64 + i*16 + l15)*32 + l4*8];
        #pragma unroll
        for (int i = 0; i < 4; ++i)
            bfr[i] = *(const short8*)&Bs[(size_t)(wc*64 + i*16 + l15)*32 + l4*8];
        #pragma unroll
        for (int mi = 0; mi < 4; ++mi)
            #pragma unroll
            for (int ni = 0; ni < 4; ++ni)
                acc[mi][ni] = __builtin_amdgcn_mfma_f32_16x16x32_bf16(af[mi], bfr[ni], acc[mi][ni], 0, 0, 0);
        __syncthreads();
    }
    #pragma unroll
    for (int mi = 0; mi < 4; ++mi) {
        #pragma unroll
        for (int ni = 0; ni < 4; ++ni) {
            #pragma unroll
            for (int r = 0; r < 4; ++r) {
                int row = tm + wr*64 + mi*16 + l4*4 + r;
                int col = tn + wc*64 + ni*16 + l15;
                float val = acc[mi][ni][r];
                if constexpr (sizeof(OutT) == 2) C[(size_t)row*N + col] = f2bf(val);
                else                             C[(size_t)row*N + col] = val;
            }
        }
    }
}

// ---------------- RoPE apply + per-head layout for Q, K ----------------
// Q is pre-scaled by 0.125*log2e so attention scores land in log2 domain.
__global__ void rope_kernel(const ushort_t* __restrict__ qkv, const float* __restrict__ sint,
                            const float* __restrict__ cost, ushort_t* __restrict__ Q,
                            ushort_t* __restrict__ Kt) {
    int i = blockIdx.x * blockDim.x + threadIdx.x; // 48*1024*32
    int d = i & 31; int p = (i >> 5) & 1023; int bh = i >> 15;
    int b = bh / NHEAD, h = bh % NHEAD;
    size_t t = (size_t)b * HW + p;
    const ushort_t* row = qkv + t * QKV_N;
    float s = sint[p*32 + d], c = cost[p*32 + d];
    float q0 = bf2f(row[h*64 + d]), q1 = bf2f(row[h*64 + d + 32]);
    float k0 = bf2f(row[768 + h*64 + d]), k1 = bf2f(row[768 + h*64 + d + 32]);
    size_t o = (size_t)bh * HW * HD + (size_t)p * HD + d;
    Q[o]      = f2bf((q0*c - q1*s) * QSCALE);
    Q[o + 32] = f2bf((q1*c + q0*s) * QSCALE);
    Kt[o]      = f2bf(k0*c - k1*s);
    Kt[o + 32] = f2bf(k1*c + k0*s);
}

// ---------------- V transpose: VT (BH, HD, HW) bf16 ----------------
__global__ void vt_kernel(const ushort_t* __restrict__ qkv, ushort_t* __restrict__ VT) {
    int i = blockIdx.x * blockDim.x + threadIdx.x; // 48*64*1024
    int p = i & 1023; int d = (i >> 10) & 63; int bh = i >> 16;
    int b = bh / NHEAD, h = bh % NHEAD;
    size_t t = (size_t)b * HW + p;
    VT[(size_t)bh * HD * HW + (size_t)d * HW + p] = qkv[t * QKV_N + 1536 + h*64 + d];
}

// ---------------- flash attention, swapped-QK^T, log2 softmax, kv-split=2 ----------------
__global__ __launch_bounds__(256) void attn_kernel(const ushort_t* __restrict__ Q,
                                                   const ushort_t* __restrict__ Kt,
                                                   const ushort_t* __restrict__ VT,
                                                   float* __restrict__ Opart,
                                                   float2* __restrict__ Ml) {
    __shared__ ushort_t P[4][16][72]; // 144B rows
    int bh = blockIdx.y;
    int split = blockIdx.z;
    int w = threadIdx.x >> 6, lane = threadIdx.x & 63;
    int l15 = lane & 15, l4 = lane >> 4;
    int qbase = blockIdx.x * 64 + w * 16;
    int q = qbase + l15;
    int qr = q >> 5, qc = q & 31;   // qr is wave-uniform (qbase is 16-aligned)
    const ushort_t* Qh = Q + (size_t)bh * HW * HD;
    const ushort_t* Kh = Kt + (size_t)bh * HW * HD;
    const ushort_t* Vh = VT + (size_t)bh * HD * HW;
    short8 aq0 = *(const short8*)&Qh[(size_t)q*64 + l4*8];
    short8 aq1 = *(const short8*)&Qh[(size_t)q*64 + 32 + l4*8];
    unsigned pat = (qc == 0) ? 3u : (7u << (qc - 1)); // 3x3 col window, clipped
    float m = -1e30f, lsum = 0.f;
    f32x4 oacc[4] = {};
    int kv0 = split * 512;

    for (int kv = kv0; kv < kv0 + 512; kv += 64) {
        // ---- QK^T (S^T tile: 64k x 16q) ----
        f32x4 s[4];
        #pragma unroll
        for (int st = 0; st < 4; ++st) {
            int kb = kv + st*16;
            short8 bk0 = *(const short8*)&Kh[(size_t)(kb + l15)*64 + l4*8];
            short8 bk1 = *(const short8*)&Kh[(size_t)(kb + l15)*64 + 32 + l4*8];
            f32x4 z = {};
            z = __builtin_amdgcn_mfma_f32_16x16x32_bf16(bk0, aq0, z, 0, 0, 0);
            z = __builtin_amdgcn_mfma_f32_16x16x32_bf16(bk1, aq1, z, 0, 0, 0);
            s[st] = z;
        }
        // ---- V fragment loads issued early (latency hidden under softmax) ----
        short8 va0[4], va1[4];
        #pragma unroll
        for (int dt = 0; dt < 4; ++dt) {
            va0[dt] = *(const short8*)&Vh[(size_t)(dt*16 + l15)*HW + kv + l4*8];
            va1[dt] = *(const short8*)&Vh[(size_t)(dt*16 + l15)*HW + kv + 32 + l4*8];
        }
        // ---- mask: only the (exactly 2) tiles overlapping rows qr-1..qr+1 ----
        int dr = qr - (kv >> 5);
        if (dr >= -1 && dr <= 2) {
            u64 tm = 0;
            if (dr >= -1 && dr <= 1) tm |= (u64)pat;          // tile row r0
            if (dr >= 0)             tm |= ((u64)pat) << 32;  // tile row r0+1 (dr<=2 given)
            u64 sub = tm >> (l4*4);
            #pragma unroll
            for (int st = 0; st < 4; ++st)
                #pragma unroll
                for (int i = 0; i < 4; ++i)
                    if ((sub >> (st*16 + i)) & 1) s[st][i] = -1e30f;
        }
        // ---- running max (log2 domain), deferred rescale ----
        float vmax = fmaxf(
            fmaxf(fmaxf(fmaxf(s[0][0], s[0][1]), fmaxf(s[0][2], s[0][3])),
                  fmaxf(fmaxf(s[1][0], s[1][1]), fmaxf(s[1][2], s[1][3]))),
            fmaxf(fmaxf(fmaxf(s[2][0], s[2][1]), fmaxf(s[2][2], s[2][3])),
                  fmaxf(fmaxf(s[3][0], s[3][1]), fmaxf(s[3][2], s[3][3]))));
        vmax = fmaxf(vmax, __shfl_xor(vmax, 16, 64));
        vmax = fmaxf(vmax, __shfl_xor(vmax, 32, 64));
        if (__any(vmax - m > 8.f)) {
            float mn = fmaxf(m, vmax);
            float sf = ex2(m - mn);
            lsum *= sf;
            #pragma unroll
            for (int dt = 0; dt < 4; ++dt)
                #pragma unroll
                for (int i = 0; i < 4; ++i) oacc[dt][i] *= sf;
            m = mn;
        }
        // ---- P = 2^(s - m), row-sum, pack to bf16 ----
        float ls = 0.f;
        #pragma unroll
        for (int st = 0; st < 4; ++st) {
            float p0 = ex2(s[st][0] - m), p1 = ex2(s[st][1] - m);
            float p2 = ex2(s[st][2] - m), p3 = ex2(s[st][3] - m);
            ls += (p0 + p1) + (p2 + p3);
            uint2 pk;
            pk.x = cvtpk(p0, p1);
            pk.y = cvtpk(p2, p3);
            *(uint2*)&P[w][l15][st*16 + l4*4] = pk;
        }
        ls += __shfl_xor(ls, 16, 64);
        ls += __shfl_xor(ls, 32, 64);
        lsum += ls;
        short8 pf0 = *(const short8*)&P[w][l15][l4*8];
        short8 pf1 = *(const short8*)&P[w][l15][32 + l4*8];
        // ---- PV: O^T += V^T * P^T ----
        #pragma unroll
        for (int dt = 0; dt < 4; ++dt) {
            oacc[dt] = __builtin_amdgcn_mfma_f32_16x16x32_bf16(va0[dt], pf0, oacc[dt], 0, 0, 0);
            oacc[dt] = __builtin_amdgcn_mfma_f32_16x16x32_bf16(va1[dt], pf1, oacc[dt], 0, 0, 0);
        }
    }
    size_t rowid = (size_t)(split*BH + bh) * HW + q;
    #pragma unroll
    for (int dt = 0; dt < 4; ++dt)
        *(f32x4*)&Opart[rowid*64 + dt*16 + l4*4] = oacc[dt];
    if (l4 == 0) Ml[rowid] = make_float2(m, lsum);
}

// ---------------- combine two kv-splits (log2 domain) ----------------
__global__ void combine_kernel(const float* __restrict__ Opart, const float2* __restrict__ Ml,
                               ushort_t* __restrict__ Ao) {
    int w = threadIdx.x >> 6, lane = threadIdx.x & 63;
    int row = blockIdx.x * 4 + w;
    int bh = row >> 10, q = row & 1023;
    int b = bh / NHEAD, h = bh % NHEAD;
    float2 ml1 = Ml[row];
    float2 ml2 = Ml[(size_t)BH*HW + row];
    float mm = fmaxf(ml1.x, ml2.x);
    float e1 = ex2(ml1.x - mm), e2 = ex2(ml2.x - mm);
    float denom = e1*ml1.y + e2*ml2.y;
    float o1 = Opart[(size_t)row*64 + lane];
    float o2 = Opart[((size_t)BH*HW + row)*64 + lane];
    float o = (e1*o1 + e2*o2) / denom;
    Ao[((size_t)b*HW + q)*D_MODEL + h*64 + lane] = f2bf(o);
}

extern "C" void kernel_launch(void* const* d_in, const int* in_sizes, int n_in,
                              void* d_out, int out_size, void* d_ws, size_t ws_size,
                              hipStream_t stream) {
    const float* x      = (const float*)d_in[0];
    const float* w_qkv  = (const float*)d_in[1];
    const float* w_out  = (const float*)d_in[2];
    const float* gamma  = (const float*)d_in[3];
    float* out = (float*)d_out;

    char* ws = (char*)d_ws;
    size_t off = 0;
    auto alloc = [&](size_t bytes) { char* p = ws + off; off += (bytes + 255) & ~255ull; return p; };
    ushort_t* xn   = (ushort_t*)alloc((size_t)TOK*D_MODEL*2);
    ushort_t* wq   = (ushort_t*)alloc((size_t)QKV_N*D_MODEL*2);
    ushort_t* wo   = (ushort_t*)alloc((size_t)D_MODEL*D_MODEL*2);
    float* sint    = (float*)alloc((size_t)HW*32*4);
    float* cost    = (float*)alloc((size_t)HW*32*4);
    ushort_t* Qr   = (ushort_t*)alloc((size_t)BH*HW*HD*2);
    ushort_t* Kr   = (ushort_t*)alloc((size_t)BH*HW*HD*2);
    ushort_t* VTt  = (ushort_t*)alloc((size_t)BH*HD*HW*2);
    ushort_t* Ao   = (ushort_t*)alloc((size_t)TOK*D_MODEL*2);
    size_t qkv_bytes   = (size_t)TOK*QKV_N*2;
    size_t opart_bytes = (size_t)2*BH*HW*64*4;
    size_t ml_bytes    = (size_t)2*BH*HW*8;
    char* big = alloc(opart_bytes + ml_bytes > qkv_bytes ? opart_bytes + ml_bytes : qkv_bytes);
    ushort_t* qkv  = (ushort_t*)big;
    float* Opart   = (float*)big;
    float2* Ml     = (float2*)(big + opart_bytes);

    rmsnorm_kernel<<<TOK/4, 256, 0, stream>>>(x, gamma, xn);
    cvt_kernel<<<(QKV_N*D_MODEL + 255)/256, 256, 0, stream>>>(w_qkv, wq, QKV_N*D_MODEL);
    cvt_kernel<<<(D_MODEL*D_MODEL + 255)/256, 256, 0, stream>>>(w_out, wo, D_MODEL*D_MODEL);
    sincos_kernel<<<HW*32/256, 256, 0, stream>>>(sint, cost);
    gemm_bt<ushort_t><<<dim3(QKV_N/128, TOK/128), 256, 0, stream>>>(xn, wq, qkv, TOK, QKV_N, D_MODEL);
    rope_kernel<<<BH*HW*32/256, 256, 0, stream>>>(qkv, sint, cost, Qr, Kr);
    vt_kernel<<<BH*HD*HW/256, 256, 0, stream>>>(qkv, VTt);
    attn_kernel<<<dim3(HW/64, BH, 2), 256, 0, stream>>>(Qr, Kr, VTt, Opart, Ml);
    combine_kernel<<<BH*HW/4, 256, 0, stream>>>(Opart, Ml, Ao);
    gemm_bt<float><<<dim3(D_MODEL/128, TOK/128), 256, 0, stream>>>(Ao, wo, out, TOK, D_MODEL, D_MODEL);
}

// Round 4
// 119.542 us; speedup vs baseline: 1.5698x; 1.5650x over previous
//
#include <hip/hip_runtime.h>

typedef __attribute__((ext_vector_type(8))) short short8;
typedef __attribute__((ext_vector_type(4))) float f32x4;
typedef unsigned short ushort_t;
typedef unsigned long long u64;

#define D_MODEL 768
#define NHEAD 12
#define HD 64
#define BATCH 4
#define HWIDTH 32
#define HW 1024
#define TOK (BATCH*HW)
#define QKV_N (3*D_MODEL)
#define BH (BATCH*NHEAD)
#define QSCALE 0.18033688f  /* 0.125 * log2(e) */

__device__ __forceinline__ ushort_t f2bf(float f) {
    union { float f; unsigned u; } v; v.f = f;
    unsigned u = v.u;
    unsigned r = u + 0x7FFFu + ((u >> 16) & 1u);
    return (ushort_t)(r >> 16);
}
__device__ __forceinline__ float bf2f(ushort_t h) {
    union { unsigned u; float f; } v; v.u = ((unsigned)h) << 16;
    return v.f;
}
__device__ __forceinline__ float ex2(float x) {
    float r; asm("v_exp_f32 %0, %1" : "=v"(r) : "v"(x)); return r;
}
__device__ __forceinline__ unsigned cvtpk(float lo, float hi) {
    unsigned r; asm("v_cvt_pk_bf16_f32 %0, %1, %2" : "=v"(r) : "v"(lo), "v"(hi)); return r;
}

// ---------------- RMSNorm: one wave per token ----------------
__global__ void rmsnorm_kernel(const float* __restrict__ x, const float* __restrict__ gamma,
                               ushort_t* __restrict__ xn) {
    int wave = threadIdx.x >> 6, lane = threadIdx.x & 63;
    int t = blockIdx.x * 4 + wave;
    const float* xr = x + (size_t)t * D_MODEL;
    float v[12]; float ss = 0.f;
    #pragma unroll
    for (int j = 0; j < 12; ++j) { v[j] = xr[lane + j*64]; ss += v[j]*v[j]; }
    #pragma unroll
    for (int m = 1; m < 64; m <<= 1) ss += __shfl_xor(ss, m, 64);
    float r = rsqrtf(ss * (1.f/768.f) + 1e-6f);
    ushort_t* o = xn + (size_t)t * D_MODEL;
    #pragma unroll
    for (int j = 0; j < 12; ++j) o[lane + j*64] = f2bf(v[j] * r * gamma[lane + j*64]);
}

// ---------------- f32 -> bf16 convert ----------------
__global__ void cvt_kernel(const float* __restrict__ in, ushort_t* __restrict__ out, int n) {
    int i = blockIdx.x * blockDim.x + threadIdx.x;
    if (i < n) out[i] = f2bf(in[i]);
}

// ---------------- axial RoPE sin/cos tables (1024 x 32) ----------------
__global__ void sincos_kernel(float* __restrict__ sint, float* __restrict__ cost) {
    int i = blockIdx.x * blockDim.x + threadIdx.x; // 32768
    int p = i >> 5, j = i & 31;
    int r = p >> 5, c = p & 31;
    int jj = j & 15;
    float freq = powf(10000.f, -(float)(2*jj) / 32.f);
    float pos = (j < 16) ? (float)r : (float)c;
    float th = pos * freq;
    sint[i] = sinf(th);
    cost[i] = cosf(th);
}

// ---------------- bf16 B^T GEMM: C[M,N] = A[M,K] * B[N,K]^T ----------------
template<typename OutT>
__global__ __launch_bounds__(256) void gemm_bt(const ushort_t* __restrict__ A,
                                               const ushort_t* __restrict__ B,
                                               OutT* __restrict__ C, int M, int N, int K) {
    __shared__ ushort_t As[128*32];
    __shared__ ushort_t Bs[128*32];
    int tn = blockIdx.x * 128, tm = blockIdx.y * 128;
    int w = threadIdx.x >> 6, lane = threadIdx.x & 63;
    int wr = w >> 1, wc = w & 1;
    int l15 = lane & 15, l4 = lane >> 4;
    f32x4 acc[4][4] = {};
    for (int k0 = 0; k0 < K; k0 += 32) {
        #pragma unroll
        for (int is = 0; is < 2; ++is) {
            int c = is*256 + w*64 + lane;
            int row = c >> 2, cc = c & 3;
            const ushort_t* ga = A + (size_t)(tm + row)*K + k0 + cc*8;
            __builtin_amdgcn_global_load_lds((const __attribute__((address_space(1))) void*)ga,
                (__attribute__((address_space(3))) void*)(As + (size_t)(is*256 + w*64)*8), 16, 0, 0);
            const ushort_t* gb = B + (size_t)(tn + row)*K + k0 + cc*8;
            __builtin_amdgcn_global_load_lds((const __attribute__((address_space(1))) void*)gb,
                (__attribute__((address_space(3))) void*)(Bs + (size_t)(is*256 + w*64)*8), 16, 0, 0);
        }
        __syncthreads();
        short8 af[4], bfr[4];
        #pragma unroll
        for (int i = 0; i < 4; ++i)
            af[i] = *(const short8*)&As[(size_t)(wr*64 + i*16 + l15)*32 + l4*8];
        #pragma unroll
        for (int i = 0; i < 4; ++i)
            bfr[i] = *(const short8*)&Bs[(size_t)(wc*64 + i*16 + l15)*32 + l4*8];
        #pragma unroll
        for (int mi = 0; mi < 4; ++mi)
            #pragma unroll
            for (int ni = 0; ni < 4; ++ni)
                acc[mi][ni] = __builtin_amdgcn_mfma_f32_16x16x32_bf16(af[mi], bfr[ni], acc[mi][ni], 0, 0, 0);
        __syncthreads();
    }
    #pragma unroll
    for (int mi = 0; mi < 4; ++mi) {
        #pragma unroll
        for (int ni = 0; ni < 4; ++ni) {
            #pragma unroll
            for (int r = 0; r < 4; ++r) {
                int row = tm + wr*64 + mi*16 + l4*4 + r;
                int col = tn + wc*64 + ni*16 + l15;
                float val = acc[mi][ni][r];
                if constexpr (sizeof(OutT) == 2) C[(size_t)row*N + col] = f2bf(val);
                else                             C[(size_t)row*N + col] = val;
            }
        }
    }
}

// ---------------- RoPE apply + per-head layout for Q, K ----------------
__global__ void rope_kernel(const ushort_t* __restrict__ qkv, const float* __restrict__ sint,
                            const float* __restrict__ cost, ushort_t* __restrict__ Q,
                            ushort_t* __restrict__ Kt) {
    int i = blockIdx.x * blockDim.x + threadIdx.x; // 48*1024*32
    int d = i & 31; int p = (i >> 5) & 1023; int bh = i >> 15;
    int b = bh / NHEAD, h = bh % NHEAD;
    size_t t = (size_t)b * HW + p;
    const ushort_t* row = qkv + t * QKV_N;
    float s = sint[p*32 + d], c = cost[p*32 + d];
    float q0 = bf2f(row[h*64 + d]), q1 = bf2f(row[h*64 + d + 32]);
    float k0 = bf2f(row[768 + h*64 + d]), k1 = bf2f(row[768 + h*64 + d + 32]);
    size_t o = (size_t)bh * HW * HD + (size_t)p * HD + d;
    Q[o]      = f2bf((q0*c - q1*s) * QSCALE);
    Q[o + 32] = f2bf((q1*c + q0*s) * QSCALE);
    Kt[o]      = f2bf(k0*c - k1*s);
    Kt[o + 32] = f2bf(k1*c + k0*s);
}

// ---------------- V transpose: VT (BH, HD, HW) bf16 ----------------
__global__ void vt_kernel(const ushort_t* __restrict__ qkv, ushort_t* __restrict__ VT) {
    int i = blockIdx.x * blockDim.x + threadIdx.x; // 48*64*1024
    int p = i & 1023; int d = (i >> 10) & 63; int bh = i >> 16;
    int b = bh / NHEAD, h = bh % NHEAD;
    size_t t = (size_t)b * HW + p;
    VT[(size_t)bh * HD * HW + (size_t)d * HW + p] = qkv[t * QKV_N + 1536 + h*64 + d];
}

// ---------------- flash attention: LDS-staged K/V, double-buffered, swizzled ----------------
// grid 768 blocks (16 qtiles x 48 bh, XCD-swizzled); 4 waves; wave: 16 q, tiles of 64 kv
__global__ __launch_bounds__(256) void attn_kernel(const ushort_t* __restrict__ Q,
                                                   const ushort_t* __restrict__ Kt,
                                                   const ushort_t* __restrict__ VT,
                                                   ushort_t* __restrict__ Ao) {
    __shared__ ushort_t Kb[2][64*64];
    __shared__ ushort_t Vb[2][64*64];
    __shared__ ushort_t P[4][16][72];
    // XCD-aware bijective swizzle: 768 blocks -> each XCD gets 6 consecutive heads
    int flat = blockIdx.x;
    int swz = (flat & 7) * 96 + (flat >> 3);
    int bh = swz >> 4;
    int qtile = swz & 15;
    int w = threadIdx.x >> 6, lane = threadIdx.x & 63;
    int l15 = lane & 15, l4 = lane >> 4;
    int qbase = qtile * 64 + w * 16;
    int q = qbase + l15;
    int qr = q >> 5, qc = q & 31;
    const ushort_t* Qh = Q + (size_t)bh * HW * HD;
    const ushort_t* Kh = Kt + (size_t)bh * HW * HD;
    const ushort_t* Vh = VT + (size_t)bh * HD * HW;
    short8 aq0 = *(const short8*)&Qh[(size_t)q*64 + l4*8];
    short8 aq1 = *(const short8*)&Qh[(size_t)q*64 + 32 + l4*8];
    unsigned pat = (qc == 0) ? 3u : (7u << (qc - 1));
    float m = -1e30f, lsum = 0.f;
    f32x4 oacc[4] = {};

    // stage K/V tile kv into buffer bufi; source pre-swizzled so LDS-linear
    // layout realizes col16' = col16 ^ (row&7)
    auto stage = [&](int bufi, int kv) {
        #pragma unroll
        for (int is = 0; is < 2; ++is) {
            int c = is*256 + w*64 + lane;       // 0..511
            int row = c >> 3;                   // local row 0..63
            int col16 = (c & 7) ^ (row & 7);
            const ushort_t* ga = Kh + (size_t)(kv + row)*64 + col16*8;
            __builtin_amdgcn_global_load_lds((const __attribute__((address_space(1))) void*)ga,
                (__attribute__((address_space(3))) void*)(&Kb[bufi][(size_t)(is*256 + w*64)*8]), 16, 0, 0);
            const ushort_t* gv = Vh + (size_t)row*HW + kv + col16*8;
            __builtin_amdgcn_global_load_lds((const __attribute__((address_space(1))) void*)gv,
                (__attribute__((address_space(3))) void*)(&Vb[bufi][(size_t)(is*256 + w*64)*8]), 16, 0, 0);
        }
    };

    int cur = 0;
    stage(0, 0);
    __syncthreads();

    for (int t = 0; t < 16; ++t) {
        int kv = t * 64;
        if (t < 15) stage(cur ^ 1, kv + 64);
        int sw = l15 & 7;
        // ---- QK^T from LDS (swizzled reads) ----
        f32x4 s[4];
        #pragma unroll
        for (int st = 0; st < 4; ++st) {
            int krow = st*16 + l15;
            short8 bk0 = *(const short8*)&Kb[cur][(size_t)krow*64 + (size_t)((l4 ^ sw))*8];
            short8 bk1 = *(const short8*)&Kb[cur][(size_t)krow*64 + (size_t)(((4+l4) ^ sw))*8];
            f32x4 z = {};
            z = __builtin_amdgcn_mfma_f32_16x16x32_bf16(bk0, aq0, z, 0, 0, 0);
            z = __builtin_amdgcn_mfma_f32_16x16x32_bf16(bk1, aq1, z, 0, 0, 0);
            s[st] = z;
        }
        // ---- V fragments from LDS (overlap with softmax) ----
        short8 va0[4], va1[4];
        #pragma unroll
        for (int dt = 0; dt < 4; ++dt) {
            int vrow = dt*16 + l15;
            va0[dt] = *(const short8*)&Vb[cur][(size_t)vrow*64 + (size_t)((l4 ^ sw))*8];
            va1[dt] = *(const short8*)&Vb[cur][(size_t)vrow*64 + (size_t)(((4+l4) ^ sw))*8];
        }
        // ---- mask: only tiles overlapping rows qr-1..qr+1 ----
        int dr = qr - (kv >> 5);
        if (dr >= -1 && dr <= 2) {
            u64 tm = 0;
            if (dr <= 1) tm |= (u64)pat;
            if (dr >= 0) tm |= ((u64)pat) << 32;
            u64 sub = tm >> (l4*4);
            #pragma unroll
            for (int st = 0; st < 4; ++st)
                #pragma unroll
                for (int i = 0; i < 4; ++i)
                    if ((sub >> (st*16 + i)) & 1) s[st][i] = -1e30f;
        }
        // ---- running max (log2 domain), deferred rescale ----
        float vmax = fmaxf(
            fmaxf(fmaxf(fmaxf(s[0][0], s[0][1]), fmaxf(s[0][2], s[0][3])),
                  fmaxf(fmaxf(s[1][0], s[1][1]), fmaxf(s[1][2], s[1][3]))),
            fmaxf(fmaxf(fmaxf(s[2][0], s[2][1]), fmaxf(s[2][2], s[2][3])),
                  fmaxf(fmaxf(s[3][0], s[3][1]), fmaxf(s[3][2], s[3][3]))));
        vmax = fmaxf(vmax, __shfl_xor(vmax, 16, 64));
        vmax = fmaxf(vmax, __shfl_xor(vmax, 32, 64));
        if (__any(vmax - m > 8.f)) {
            float mn = fmaxf(m, vmax);
            float sf = ex2(m - mn);
            lsum *= sf;
            #pragma unroll
            for (int dt = 0; dt < 4; ++dt)
                #pragma unroll
                for (int i = 0; i < 4; ++i) oacc[dt][i] *= sf;
            m = mn;
        }
        // ---- P = 2^(s-m), row-sum, pack bf16 ----
        float ls = 0.f;
        #pragma unroll
        for (int st = 0; st < 4; ++st) {
            float p0 = ex2(s[st][0] - m), p1 = ex2(s[st][1] - m);
            float p2 = ex2(s[st][2] - m), p3 = ex2(s[st][3] - m);
            ls += (p0 + p1) + (p2 + p3);
            uint2 pk;
            pk.x = cvtpk(p0, p1);
            pk.y = cvtpk(p2, p3);
            *(uint2*)&P[w][l15][st*16 + l4*4] = pk;
        }
        ls += __shfl_xor(ls, 16, 64);
        ls += __shfl_xor(ls, 32, 64);
        lsum += ls;
        short8 pf0 = *(const short8*)&P[w][l15][l4*8];
        short8 pf1 = *(const short8*)&P[w][l15][32 + l4*8];
        // ---- PV: O^T += V^T * P^T ----
        #pragma unroll
        for (int dt = 0; dt < 4; ++dt) {
            oacc[dt] = __builtin_amdgcn_mfma_f32_16x16x32_bf16(va0[dt], pf0, oacc[dt], 0, 0, 0);
            oacc[dt] = __builtin_amdgcn_mfma_f32_16x16x32_bf16(va1[dt], pf1, oacc[dt], 0, 0, 0);
        }
        __syncthreads();
        cur ^= 1;
    }
    // ---- write Ao directly (bf16) ----
    int b = bh / NHEAD, h = bh % NHEAD;
    float rl = 1.f / lsum;
    size_t obase = ((size_t)b*HW + q)*D_MODEL + h*64;
    #pragma unroll
    for (int dt = 0; dt < 4; ++dt) {
        uint2 pk;
        pk.x = cvtpk(oacc[dt][0]*rl, oacc[dt][1]*rl);
        pk.y = cvtpk(oacc[dt][2]*rl, oacc[dt][3]*rl);
        *(uint2*)&Ao[obase + dt*16 + l4*4] = pk;
    }
}

extern "C" void kernel_launch(void* const* d_in, const int* in_sizes, int n_in,
                              void* d_out, int out_size, void* d_ws, size_t ws_size,
                              hipStream_t stream) {
    const float* x      = (const float*)d_in[0];
    const float* w_qkv  = (const float*)d_in[1];
    const float* w_out  = (const float*)d_in[2];
    const float* gamma  = (const float*)d_in[3];
    float* out = (float*)d_out;

    char* ws = (char*)d_ws;
    size_t off = 0;
    auto alloc = [&](size_t bytes) { char* p = ws + off; off += (bytes + 255) & ~255ull; return p; };
    ushort_t* xn   = (ushort_t*)alloc((size_t)TOK*D_MODEL*2);
    ushort_t* wq   = (ushort_t*)alloc((size_t)QKV_N*D_MODEL*2);
    ushort_t* wo   = (ushort_t*)alloc((size_t)D_MODEL*D_MODEL*2);
    float* sint    = (float*)alloc((size_t)HW*32*4);
    float* cost    = (float*)alloc((size_t)HW*32*4);
    ushort_t* Qr   = (ushort_t*)alloc((size_t)BH*HW*HD*2);
    ushort_t* Kr   = (ushort_t*)alloc((size_t)BH*HW*HD*2);
    ushort_t* VTt  = (ushort_t*)alloc((size_t)BH*HD*HW*2);
    ushort_t* Ao   = (ushort_t*)alloc((size_t)TOK*D_MODEL*2);
    ushort_t* qkv  = (ushort_t*)alloc((size_t)TOK*QKV_N*2);

    rmsnorm_kernel<<<TOK/4, 256, 0, stream>>>(x, gamma, xn);
    cvt_kernel<<<(QKV_N*D_MODEL + 255)/256, 256, 0, stream>>>(w_qkv, wq, QKV_N*D_MODEL);
    cvt_kernel<<<(D_MODEL*D_MODEL + 255)/256, 256, 0, stream>>>(w_out, wo, D_MODEL*D_MODEL);
    sincos_kernel<<<HW*32/256, 256, 0, stream>>>(sint, cost);
    gemm_bt<ushort_t><<<dim3(QKV_N/128, TOK/128), 256, 0, stream>>>(xn, wq, qkv, TOK, QKV_N, D_MODEL);
    rope_kernel<<<BH*HW*32/256, 256, 0, stream>>>(qkv, sint, cost, Qr, Kr);
    vt_kernel<<<BH*HD*HW/256, 256, 0, stream>>>(qkv, VTt);
    attn_kernel<<<768, 256, 0, stream>>>(Qr, Kr, VTt, Ao);
    gemm_bt<float><<<dim3(D_MODEL/128, TOK/128), 256, 0, stream>>>(Ao, wo, out, TOK, D_MODEL, D_MODEL);
}

// Round 5
// 109.570 us; speedup vs baseline: 1.7126x; 1.0910x over previous
//
#include <hip/hip_runtime.h>

typedef __attribute__((ext_vector_type(8))) short short8;
typedef __attribute__((ext_vector_type(4))) float f32x4;
typedef __attribute__((ext_vector_type(4))) unsigned short ushort4_t;
typedef unsigned short ushort_t;
typedef unsigned long long u64;

#define D_MODEL 768
#define NHEAD 12
#define HD 64
#define BATCH 4
#define HWIDTH 32
#define HW 1024
#define TOK (BATCH*HW)
#define QKV_N (3*D_MODEL)
#define BH (BATCH*NHEAD)
#define QSCALE 0.18033688f  /* 0.125 * log2(e) */

__device__ __forceinline__ ushort_t f2bf(float f) {
    union { float f; unsigned u; } v; v.f = f;
    unsigned u = v.u;
    unsigned r = u + 0x7FFFu + ((u >> 16) & 1u);
    return (ushort_t)(r >> 16);
}
__device__ __forceinline__ float bf2f(ushort_t h) {
    union { unsigned u; float f; } v; v.u = ((unsigned)h) << 16;
    return v.f;
}
__device__ __forceinline__ float ex2(float x) {
    float r; asm("v_exp_f32 %0, %1" : "=v"(r) : "v"(x)); return r;
}
__device__ __forceinline__ unsigned cvtpk(float lo, float hi) {
    unsigned r; asm("v_cvt_pk_bf16_f32 %0, %1, %2" : "=v"(r) : "v"(lo), "v"(hi)); return r;
}

// ---------------- RMSNorm: one wave per token ----------------
__global__ void rmsnorm_kernel(const float* __restrict__ x, const float* __restrict__ gamma,
                               ushort_t* __restrict__ xn) {
    int wave = threadIdx.x >> 6, lane = threadIdx.x & 63;
    int t = blockIdx.x * 4 + wave;
    const float* xr = x + (size_t)t * D_MODEL;
    float v[12]; float ss = 0.f;
    #pragma unroll
    for (int j = 0; j < 12; ++j) { v[j] = xr[lane + j*64]; ss += v[j]*v[j]; }
    #pragma unroll
    for (int m = 1; m < 64; m <<= 1) ss += __shfl_xor(ss, m, 64);
    float r = rsqrtf(ss * (1.f/768.f) + 1e-6f);
    ushort_t* o = xn + (size_t)t * D_MODEL;
    #pragma unroll
    for (int j = 0; j < 12; ++j) o[lane + j*64] = f2bf(v[j] * r * gamma[lane + j*64]);
}

// ---------------- f32 -> bf16 convert ----------------
__global__ void cvt_kernel(const float* __restrict__ in, ushort_t* __restrict__ out, int n) {
    int i = blockIdx.x * blockDim.x + threadIdx.x;
    if (i < n) out[i] = f2bf(in[i]);
}

// ---------------- axial RoPE sin/cos tables (1024 x 32) ----------------
__global__ void sincos_kernel(float* __restrict__ sint, float* __restrict__ cost) {
    int i = blockIdx.x * blockDim.x + threadIdx.x; // 32768
    int p = i >> 5, j = i & 31;
    int r = p >> 5, c = p & 31;
    int jj = j & 15;
    float freq = powf(10000.f, -(float)(2*jj) / 32.f);
    float pos = (j < 16) ? (float)r : (float)c;
    float th = pos * freq;
    sint[i] = sinf(th);
    cost[i] = cosf(th);
}

// ---------------- qkv GEMM with fused RoPE + layout epilogue ----------------
// C-tile cols: [0,768)=Q(RoPE,scaled), [768,1536)=K(RoPE), [1536,2304)=V(transposed)
__global__ __launch_bounds__(256) void gemm_qkv_rope(const ushort_t* __restrict__ A,
                                                     const ushort_t* __restrict__ B,
                                                     const float* __restrict__ sint,
                                                     const float* __restrict__ cost,
                                                     ushort_t* __restrict__ Qr,
                                                     ushort_t* __restrict__ Kr,
                                                     ushort_t* __restrict__ VTt) {
    __shared__ ushort_t As[128*32];
    __shared__ ushort_t Bs[128*32];
    const int K = D_MODEL;
    int tn = blockIdx.x * 128, tm = blockIdx.y * 128;
    int w = threadIdx.x >> 6, lane = threadIdx.x & 63;
    int wr = w >> 1, wc = w & 1;
    int l15 = lane & 15, l4 = lane >> 4;
    f32x4 acc[4][4] = {};
    for (int k0 = 0; k0 < K; k0 += 32) {
        #pragma unroll
        for (int is = 0; is < 2; ++is) {
            int c = is*256 + w*64 + lane;
            int row = c >> 2, cc = c & 3;
            const ushort_t* ga = A + (size_t)(tm + row)*K + k0 + cc*8;
            __builtin_amdgcn_global_load_lds((const __attribute__((address_space(1))) void*)ga,
                (__attribute__((address_space(3))) void*)(As + (size_t)(is*256 + w*64)*8), 16, 0, 0);
            const ushort_t* gb = B + (size_t)(tn + row)*K + k0 + cc*8;
            __builtin_amdgcn_global_load_lds((const __attribute__((address_space(1))) void*)gb,
                (__attribute__((address_space(3))) void*)(Bs + (size_t)(is*256 + w*64)*8), 16, 0, 0);
        }
        __syncthreads();
        short8 af[4], bfr[4];
        #pragma unroll
        for (int i = 0; i < 4; ++i)
            af[i] = *(const short8*)&As[(size_t)(wr*64 + i*16 + l15)*32 + l4*8];
        #pragma unroll
        for (int i = 0; i < 4; ++i)
            bfr[i] = *(const short8*)&Bs[(size_t)(wc*64 + i*16 + l15)*32 + l4*8];
        #pragma unroll
        for (int mi = 0; mi < 4; ++mi)
            #pragma unroll
            for (int ni = 0; ni < 4; ++ni)
                acc[mi][ni] = __builtin_amdgcn_mfma_f32_16x16x32_bf16(af[mi], bfr[ni], acc[mi][ni], 0, 0, 0);
        __syncthreads();
    }
    // ---- fused epilogue ----
    int col_base = tn + wc*64;         // 64-aligned; one head
    int region = col_base / 768;       // 0=Q 1=K 2=V (wave-uniform)
    int h = (col_base % 768) >> 6;     // head index
    if (region < 2) {
        ushort_t* dst = (region == 0) ? Qr : Kr;
        float scale = (region == 0) ? QSCALE : 1.f;
        #pragma unroll
        for (int mi = 0; mi < 4; ++mi) {
            #pragma unroll
            for (int ni = 0; ni < 2; ++ni) {
                int d = ni*16 + l15;   // 0..31
                #pragma unroll
                for (int r = 0; r < 4; ++r) {
                    int pt = tm + wr*64 + mi*16 + l4*4 + r;
                    int b = pt >> 10, p = pt & 1023;
                    float s = sint[p*32 + d], c = cost[p*32 + d];
                    float t0 = acc[mi][ni][r], t1 = acc[mi][ni+2][r];
                    size_t o = (size_t)(b*NHEAD + h)*HW*HD + (size_t)p*HD + d;
                    dst[o]      = f2bf((t0*c - t1*s) * scale);
                    dst[o + 32] = f2bf((t1*c + t0*s) * scale);
                }
            }
        }
    } else {
        #pragma unroll
        for (int mi = 0; mi < 4; ++mi) {
            int pt = tm + wr*64 + mi*16 + l4*4;
            int b = pt >> 10, p = pt & 1023;
            size_t hb = (size_t)(b*NHEAD + h)*HD*HW;
            #pragma unroll
            for (int ni = 0; ni < 4; ++ni) {
                int d = ni*16 + l15;
                ushort4_t pk;
                pk.x = f2bf(acc[mi][ni][0]);
                pk.y = f2bf(acc[mi][ni][1]);
                pk.z = f2bf(acc[mi][ni][2]);
                pk.w = f2bf(acc[mi][ni][3]);
                *(ushort4_t*)&VTt[hb + (size_t)d*HW + p] = pk;
            }
        }
    }
}

// ---------------- bf16 B^T GEMM (plain epilogue, f32 out) ----------------
__global__ __launch_bounds__(256) void gemm_bt_f32(const ushort_t* __restrict__ A,
                                                   const ushort_t* __restrict__ B,
                                                   float* __restrict__ C, int M, int N, int K) {
    __shared__ ushort_t As[128*32];
    __shared__ ushort_t Bs[128*32];
    int tn = blockIdx.x * 128, tm = blockIdx.y * 128;
    int w = threadIdx.x >> 6, lane = threadIdx.x & 63;
    int wr = w >> 1, wc = w & 1;
    int l15 = lane & 15, l4 = lane >> 4;
    f32x4 acc[4][4] = {};
    for (int k0 = 0; k0 < K; k0 += 32) {
        #pragma unroll
        for (int is = 0; is < 2; ++is) {
            int c = is*256 + w*64 + lane;
            int row = c >> 2, cc = c & 3;
            const ushort_t* ga = A + (size_t)(tm + row)*K + k0 + cc*8;
            __builtin_amdgcn_global_load_lds((const __attribute__((address_space(1))) void*)ga,
                (__attribute__((address_space(3))) void*)(As + (size_t)(is*256 + w*64)*8), 16, 0, 0);
            const ushort_t* gb = B + (size_t)(tn + row)*K + k0 + cc*8;
            __builtin_amdgcn_global_load_lds((const __attribute__((address_space(1))) void*)gb,
                (__attribute__((address_space(3))) void*)(Bs + (size_t)(is*256 + w*64)*8), 16, 0, 0);
        }
        __syncthreads();
        short8 af[4], bfr[4];
        #pragma unroll
        for (int i = 0; i < 4; ++i)
            af[i] = *(const short8*)&As[(size_t)(wr*64 + i*16 + l15)*32 + l4*8];
        #pragma unroll
        for (int i = 0; i < 4; ++i)
            bfr[i] = *(const short8*)&Bs[(size_t)(wc*64 + i*16 + l15)*32 + l4*8];
        #pragma unroll
        for (int mi = 0; mi < 4; ++mi)
            #pragma unroll
            for (int ni = 0; ni < 4; ++ni)
                acc[mi][ni] = __builtin_amdgcn_mfma_f32_16x16x32_bf16(af[mi], bfr[ni], acc[mi][ni], 0, 0, 0);
        __syncthreads();
    }
    #pragma unroll
    for (int mi = 0; mi < 4; ++mi)
        #pragma unroll
        for (int ni = 0; ni < 4; ++ni)
            #pragma unroll
            for (int r = 0; r < 4; ++r) {
                int row = tm + wr*64 + mi*16 + l4*4 + r;
                int col = tn + wc*64 + ni*16 + l15;
                C[(size_t)row*N + col] = acc[mi][ni][r];
            }
}

// ---------------- flash attention: LDS-staged K/V, double-buffered, swizzled ----------------
__global__ __launch_bounds__(256) void attn_kernel(const ushort_t* __restrict__ Q,
                                                   const ushort_t* __restrict__ Kt,
                                                   const ushort_t* __restrict__ VT,
                                                   ushort_t* __restrict__ Ao) {
    __shared__ ushort_t Kb[2][64*64];
    __shared__ ushort_t Vb[2][64*64];
    __shared__ ushort_t P[4][16][72];
    int flat = blockIdx.x;
    int swz = (flat & 7) * 96 + (flat >> 3);
    int bh = swz >> 4;
    int qtile = swz & 15;
    int w = threadIdx.x >> 6, lane = threadIdx.x & 63;
    int l15 = lane & 15, l4 = lane >> 4;
    int qbase = qtile * 64 + w * 16;
    int q = qbase + l15;
    int qr = q >> 5, qc = q & 31;
    const ushort_t* Qh = Q + (size_t)bh * HW * HD;
    const ushort_t* Kh = Kt + (size_t)bh * HW * HD;
    const ushort_t* Vh = VT + (size_t)bh * HD * HW;
    short8 aq0 = *(const short8*)&Qh[(size_t)q*64 + l4*8];
    short8 aq1 = *(const short8*)&Qh[(size_t)q*64 + 32 + l4*8];
    unsigned pat = (qc == 0) ? 3u : (7u << (qc - 1));
    float m = -1e30f, lsum = 0.f;
    f32x4 oacc[4] = {};

    auto stage = [&](int bufi, int kv) {
        #pragma unroll
        for (int is = 0; is < 2; ++is) {
            int c = is*256 + w*64 + lane;
            int row = c >> 3;
            int col16 = (c & 7) ^ (row & 7);
            const ushort_t* ga = Kh + (size_t)(kv + row)*64 + col16*8;
            __builtin_amdgcn_global_load_lds((const __attribute__((address_space(1))) void*)ga,
                (__attribute__((address_space(3))) void*)(&Kb[bufi][(size_t)(is*256 + w*64)*8]), 16, 0, 0);
            const ushort_t* gv = Vh + (size_t)row*HW + kv + col16*8;
            __builtin_amdgcn_global_load_lds((const __attribute__((address_space(1))) void*)gv,
                (__attribute__((address_space(3))) void*)(&Vb[bufi][(size_t)(is*256 + w*64)*8]), 16, 0, 0);
        }
    };

    int cur = 0;
    stage(0, 0);
    __syncthreads();

    for (int t = 0; t < 16; ++t) {
        int kv = t * 64;
        if (t < 15) stage(cur ^ 1, kv + 64);
        int sw = l15 & 7;
        f32x4 s[4];
        #pragma unroll
        for (int st = 0; st < 4; ++st) {
            int krow = st*16 + l15;
            short8 bk0 = *(const short8*)&Kb[cur][(size_t)krow*64 + (size_t)((l4 ^ sw))*8];
            short8 bk1 = *(const short8*)&Kb[cur][(size_t)krow*64 + (size_t)(((4+l4) ^ sw))*8];
            f32x4 z = {};
            z = __builtin_amdgcn_mfma_f32_16x16x32_bf16(bk0, aq0, z, 0, 0, 0);
            z = __builtin_amdgcn_mfma_f32_16x16x32_bf16(bk1, aq1, z, 0, 0, 0);
            s[st] = z;
        }
        short8 va0[4], va1[4];
        #pragma unroll
        for (int dt = 0; dt < 4; ++dt) {
            int vrow = dt*16 + l15;
            va0[dt] = *(const short8*)&Vb[cur][(size_t)vrow*64 + (size_t)((l4 ^ sw))*8];
            va1[dt] = *(const short8*)&Vb[cur][(size_t)vrow*64 + (size_t)(((4+l4) ^ sw))*8];
        }
        int dr = qr - (kv >> 5);
        if (dr >= -1 && dr <= 2) {
            u64 tm = 0;
            if (dr <= 1) tm |= (u64)pat;
            if (dr >= 0) tm |= ((u64)pat) << 32;
            u64 sub = tm >> (l4*4);
            #pragma unroll
            for (int st = 0; st < 4; ++st)
                #pragma unroll
                for (int i = 0; i < 4; ++i)
                    if ((sub >> (st*16 + i)) & 1) s[st][i] = -1e30f;
        }
        float vmax = fmaxf(
            fmaxf(fmaxf(fmaxf(s[0][0], s[0][1]), fmaxf(s[0][2], s[0][3])),
                  fmaxf(fmaxf(s[1][0], s[1][1]), fmaxf(s[1][2], s[1][3]))),
            fmaxf(fmaxf(fmaxf(s[2][0], s[2][1]), fmaxf(s[2][2], s[2][3])),
                  fmaxf(fmaxf(s[3][0], s[3][1]), fmaxf(s[3][2], s[3][3]))));
        vmax = fmaxf(vmax, __shfl_xor(vmax, 16, 64));
        vmax = fmaxf(vmax, __shfl_xor(vmax, 32, 64));
        if (__any(vmax - m > 8.f)) {
            float mn = fmaxf(m, vmax);
            float sf = ex2(m - mn);
            lsum *= sf;
            #pragma unroll
            for (int dt = 0; dt < 4; ++dt)
                #pragma unroll
                for (int i = 0; i < 4; ++i) oacc[dt][i] *= sf;
            m = mn;
        }
        float ls = 0.f;
        #pragma unroll
        for (int st = 0; st < 4; ++st) {
            float p0 = ex2(s[st][0] - m), p1 = ex2(s[st][1] - m);
            float p2 = ex2(s[st][2] - m), p3 = ex2(s[st][3] - m);
            ls += (p0 + p1) + (p2 + p3);
            uint2 pk;
            pk.x = cvtpk(p0, p1);
            pk.y = cvtpk(p2, p3);
            *(uint2*)&P[w][l15][st*16 + l4*4] = pk;
        }
        ls += __shfl_xor(ls, 16, 64);
        ls += __shfl_xor(ls, 32, 64);
        lsum += ls;
        short8 pf0 = *(const short8*)&P[w][l15][l4*8];
        short8 pf1 = *(const short8*)&P[w][l15][32 + l4*8];
        #pragma unroll
        for (int dt = 0; dt < 4; ++dt) {
            oacc[dt] = __builtin_amdgcn_mfma_f32_16x16x32_bf16(va0[dt], pf0, oacc[dt], 0, 0, 0);
            oacc[dt] = __builtin_amdgcn_mfma_f32_16x16x32_bf16(va1[dt], pf1, oacc[dt], 0, 0, 0);
        }
        __syncthreads();
        cur ^= 1;
    }
    int b = bh / NHEAD, h = bh % NHEAD;
    float rl = 1.f / lsum;
    size_t obase = ((size_t)b*HW + q)*D_MODEL + h*64;
    #pragma unroll
    for (int dt = 0; dt < 4; ++dt) {
        uint2 pk;
        pk.x = cvtpk(oacc[dt][0]*rl, oacc[dt][1]*rl);
        pk.y = cvtpk(oacc[dt][2]*rl, oacc[dt][3]*rl);
        *(uint2*)&Ao[obase + dt*16 + l4*4] = pk;
    }
}

extern "C" void kernel_launch(void* const* d_in, const int* in_sizes, int n_in,
                              void* d_out, int out_size, void* d_ws, size_t ws_size,
                              hipStream_t stream) {
    const float* x      = (const float*)d_in[0];
    const float* w_qkv  = (const float*)d_in[1];
    const float* w_out  = (const float*)d_in[2];
    const float* gamma  = (const float*)d_in[3];
    float* out = (float*)d_out;

    char* ws = (char*)d_ws;
    size_t off = 0;
    auto alloc = [&](size_t bytes) { char* p = ws + off; off += (bytes + 255) & ~255ull; return p; };
    ushort_t* xn   = (ushort_t*)alloc((size_t)TOK*D_MODEL*2);
    ushort_t* wq   = (ushort_t*)alloc((size_t)QKV_N*D_MODEL*2);
    ushort_t* wo   = (ushort_t*)alloc((size_t)D_MODEL*D_MODEL*2);
    float* sint    = (float*)alloc((size_t)HW*32*4);
    float* cost    = (float*)alloc((size_t)HW*32*4);
    ushort_t* Qr   = (ushort_t*)alloc((size_t)BH*HW*HD*2);
    ushort_t* Kr   = (ushort_t*)alloc((size_t)BH*HW*HD*2);
    ushort_t* VTt  = (ushort_t*)alloc((size_t)BH*HD*HW*2);
    ushort_t* Ao   = (ushort_t*)alloc((size_t)TOK*D_MODEL*2);

    rmsnorm_kernel<<<TOK/4, 256, 0, stream>>>(x, gamma, xn);
    cvt_kernel<<<(QKV_N*D_MODEL + 255)/256, 256, 0, stream>>>(w_qkv, wq, QKV_N*D_MODEL);
    cvt_kernel<<<(D_MODEL*D_MODEL + 255)/256, 256, 0, stream>>>(w_out, wo, D_MODEL*D_MODEL);
    sincos_kernel<<<HW*32/256, 256, 0, stream>>>(sint, cost);
    gemm_qkv_rope<<<dim3(QKV_N/128, TOK/128), 256, 0, stream>>>(xn, wq, sint, cost, Qr, Kr, VTt);
    attn_kernel<<<768, 256, 0, stream>>>(Qr, Kr, VTt, Ao);
    gemm_bt_f32<<<dim3(D_MODEL/128, TOK/128), 256, 0, stream>>>(Ao, wo, out, TOK, D_MODEL, D_MODEL);
}

// Round 6
// 106.766 us; speedup vs baseline: 1.7576x; 1.0263x over previous
//
#include <hip/hip_runtime.h>

typedef __attribute__((ext_vector_type(8))) short short8;
typedef __attribute__((ext_vector_type(4))) float f32x4;
typedef __attribute__((ext_vector_type(4))) unsigned short ushort4_t;
typedef unsigned short ushort_t;
typedef unsigned long long u64;

#define D_MODEL 768
#define NHEAD 12
#define HD 64
#define BATCH 4
#define HWIDTH 32
#define HW 1024
#define TOK (BATCH*HW)
#define QKV_N (3*D_MODEL)
#define BH (BATCH*NHEAD)
#define QSCALE 0.18033688f  /* 0.125 * log2(e) */

__device__ __forceinline__ ushort_t f2bf(float f) {
    union { float f; unsigned u; } v; v.f = f;
    unsigned u = v.u;
    unsigned r = u + 0x7FFFu + ((u >> 16) & 1u);
    return (ushort_t)(r >> 16);
}
__device__ __forceinline__ float bf2f(ushort_t h) {
    union { unsigned u; float f; } v; v.u = ((unsigned)h) << 16;
    return v.f;
}
__device__ __forceinline__ float ex2(float x) {
    float r; asm("v_exp_f32 %0, %1" : "=v"(r) : "v"(x)); return r;
}
__device__ __forceinline__ unsigned cvtpk(float lo, float hi) {
    unsigned r; asm("v_cvt_pk_bf16_f32 %0, %1, %2" : "=v"(r) : "v"(lo), "v"(hi)); return r;
}

// ---------------- RMSNorm: one wave per token ----------------
__global__ void rmsnorm_kernel(const float* __restrict__ x, const float* __restrict__ gamma,
                               ushort_t* __restrict__ xn) {
    int wave = threadIdx.x >> 6, lane = threadIdx.x & 63;
    int t = blockIdx.x * 4 + wave;
    const float* xr = x + (size_t)t * D_MODEL;
    float v[12]; float ss = 0.f;
    #pragma unroll
    for (int j = 0; j < 12; ++j) { v[j] = xr[lane + j*64]; ss += v[j]*v[j]; }
    #pragma unroll
    for (int m = 1; m < 64; m <<= 1) ss += __shfl_xor(ss, m, 64);
    float r = rsqrtf(ss * (1.f/768.f) + 1e-6f);
    ushort_t* o = xn + (size_t)t * D_MODEL;
    #pragma unroll
    for (int j = 0; j < 12; ++j) o[lane + j*64] = f2bf(v[j] * r * gamma[lane + j*64]);
}

// ---------------- f32 -> bf16 convert ----------------
__global__ void cvt_kernel(const float* __restrict__ in, ushort_t* __restrict__ out, int n) {
    int i = blockIdx.x * blockDim.x + threadIdx.x;
    if (i < n) out[i] = f2bf(in[i]);
}

// ---------------- axial RoPE sin/cos tables (1024 x 32) ----------------
__global__ void sincos_kernel(float* __restrict__ sint, float* __restrict__ cost) {
    int i = blockIdx.x * blockDim.x + threadIdx.x; // 32768
    int p = i >> 5, j = i & 31;
    int r = p >> 5, c = p & 31;
    int jj = j & 15;
    float freq = powf(10000.f, -(float)(2*jj) / 32.f);
    float pos = (j < 16) ? (float)r : (float)c;
    float th = pos * freq;
    sint[i] = sinf(th);
    cost[i] = cosf(th);
}

// ---------------- barrier-free 1-wave 64x64 GEMM, counted-vmcnt pipeline ----------------
// C[M=4096, N=64*NT] = A[M,768] * B[N,768]^T.  EPI: 0 = fused RoPE/V-layout, 1 = f32 out.
template<int NT, int EPI>
__global__ __launch_bounds__(64, 3) void gemm64(const ushort_t* __restrict__ A,
                                                const ushort_t* __restrict__ B,
                                                const float* __restrict__ sint,
                                                const float* __restrict__ cost,
                                                ushort_t* __restrict__ Qr,
                                                ushort_t* __restrict__ Kr,
                                                ushort_t* __restrict__ VTt,
                                                float* __restrict__ C) {
    __shared__ ushort_t As[2][64*32];
    __shared__ ushort_t Bs[2][64*32];
    const int K = 768;
    // chunked bijective XCD swizzle: logical = (i%8)*(8*NT) + i/8
    int logical = (blockIdx.x & 7) * (8*NT) + (blockIdx.x >> 3);
    int mtile = logical / NT, ntile = logical % NT;
    int tm = mtile * 64, tn = ntile * 64;
    int lane = threadIdx.x;
    int l15 = lane & 15, l4 = lane >> 4;

    // staging: per issue j (0..3), 64 lanes x 16B = 8 rows of 32 bf16.
    // slot pre-swizzled so LDS-linear layout realizes slot' = slot ^ (row&3).
    int srow = lane >> 2;                       // 0..15 (+ j*16)
    int sslot = (lane & 3) ^ (srow & 3);
    const ushort_t* Abase = A + (size_t)(tm + srow)*K + sslot*8;
    const ushort_t* Bbase = B + (size_t)(tn + srow)*K + sslot*8;

    auto issue = [&](int buf, int k0) {
        #pragma unroll
        for (int j = 0; j < 4; ++j) {
            const ushort_t* ga = Abase + (size_t)(j*16)*K + k0;
            __builtin_amdgcn_global_load_lds((const __attribute__((address_space(1))) void*)ga,
                (__attribute__((address_space(3))) void*)(&As[buf][j*512]), 16, 0, 0);
            const ushort_t* gb = Bbase + (size_t)(j*16)*K + k0;
            __builtin_amdgcn_global_load_lds((const __attribute__((address_space(1))) void*)gb,
                (__attribute__((address_space(3))) void*)(&Bs[buf][j*512]), 16, 0, 0);
        }
    };

    // fragment read offset: row = mi*16 + l15 (row&3 == l15&3), slot = l4 ^ (l15&3)
    int frag_off = l15*32 + (l4 ^ (l15 & 3))*8;

    f32x4 acc[4][4] = {};
    issue(0, 0);
    for (int t = 0; t < 24; ++t) {
        int k1 = (t < 23) ? (t+1)*32 : 0;       // t=23: dummy refill (unread)
        issue((t+1) & 1, k1);
        asm volatile("s_waitcnt vmcnt(8)" ::: "memory");
        int bi = t & 1;
        short8 af[4], bfr[4];
        #pragma unroll
        for (int i = 0; i < 4; ++i) af[i]  = *(const short8*)&As[bi][i*512 + frag_off];
        #pragma unroll
        for (int i = 0; i < 4; ++i) bfr[i] = *(const short8*)&Bs[bi][i*512 + frag_off];
        #pragma unroll
        for (int mi = 0; mi < 4; ++mi)
            #pragma unroll
            for (int ni = 0; ni < 4; ++ni)
                acc[mi][ni] = __builtin_amdgcn_mfma_f32_16x16x32_bf16(af[mi], bfr[ni], acc[mi][ni], 0, 0, 0);
    }

    if constexpr (EPI == 0) {
        // cols tn..tn+63 = one head of one region
        int region = tn / 768;          // 0=Q 1=K 2=V
        int h = (tn % 768) >> 6;
        if (region < 2) {
            ushort_t* dst = (region == 0) ? Qr : Kr;
            float scale = (region == 0) ? QSCALE : 1.f;
            #pragma unroll
            for (int mi = 0; mi < 4; ++mi) {
                #pragma unroll
                for (int ni = 0; ni < 2; ++ni) {
                    int d = ni*16 + l15;
                    #pragma unroll
                    for (int r = 0; r < 4; ++r) {
                        int pt = tm + mi*16 + l4*4 + r;
                        int b = pt >> 10, p = pt & 1023;
                        float s = sint[p*32 + d], c = cost[p*32 + d];
                        float t0 = acc[mi][ni][r], t1 = acc[mi][ni+2][r];
                        size_t o = (size_t)(b*NHEAD + h)*HW*HD + (size_t)p*HD + d;
                        dst[o]      = f2bf((t0*c - t1*s) * scale);
                        dst[o + 32] = f2bf((t1*c + t0*s) * scale);
                    }
                }
            }
        } else {
            #pragma unroll
            for (int mi = 0; mi < 4; ++mi) {
                int pt = tm + mi*16 + l4*4;
                int b = pt >> 10, p = pt & 1023;
                size_t hb = (size_t)(b*NHEAD + h)*HD*HW;
                #pragma unroll
                for (int ni = 0; ni < 4; ++ni) {
                    int d = ni*16 + l15;
                    ushort4_t pk;
                    pk.x = f2bf(acc[mi][ni][0]);
                    pk.y = f2bf(acc[mi][ni][1]);
                    pk.z = f2bf(acc[mi][ni][2]);
                    pk.w = f2bf(acc[mi][ni][3]);
                    *(ushort4_t*)&VTt[hb + (size_t)d*HW + p] = pk;
                }
            }
        }
    } else {
        #pragma unroll
        for (int mi = 0; mi < 4; ++mi)
            #pragma unroll
            for (int ni = 0; ni < 4; ++ni)
                #pragma unroll
                for (int r = 0; r < 4; ++r) {
                    int row = tm + mi*16 + l4*4 + r;
                    int col = tn + ni*16 + l15;
                    C[(size_t)row*(64*NT) + col] = acc[mi][ni][r];
                }
    }
}

// ---------------- flash attention: LDS-staged K/V, double-buffered, swizzled ----------------
__global__ __launch_bounds__(256) void attn_kernel(const ushort_t* __restrict__ Q,
                                                   const ushort_t* __restrict__ Kt,
                                                   const ushort_t* __restrict__ VT,
                                                   ushort_t* __restrict__ Ao) {
    __shared__ ushort_t Kb[2][64*64];
    __shared__ ushort_t Vb[2][64*64];
    __shared__ ushort_t P[4][16][72];
    int flat = blockIdx.x;
    int swz = (flat & 7) * 96 + (flat >> 3);
    int bh = swz >> 4;
    int qtile = swz & 15;
    int w = threadIdx.x >> 6, lane = threadIdx.x & 63;
    int l15 = lane & 15, l4 = lane >> 4;
    int qbase = qtile * 64 + w * 16;
    int q = qbase + l15;
    int qr = q >> 5, qc = q & 31;
    const ushort_t* Qh = Q + (size_t)bh * HW * HD;
    const ushort_t* Kh = Kt + (size_t)bh * HW * HD;
    const ushort_t* Vh = VT + (size_t)bh * HD * HW;
    short8 aq0 = *(const short8*)&Qh[(size_t)q*64 + l4*8];
    short8 aq1 = *(const short8*)&Qh[(size_t)q*64 + 32 + l4*8];
    unsigned pat = (qc == 0) ? 3u : (7u << (qc - 1));
    float m = -1e30f, lsum = 0.f;
    f32x4 oacc[4] = {};

    auto stage = [&](int bufi, int kv) {
        #pragma unroll
        for (int is = 0; is < 2; ++is) {
            int c = is*256 + w*64 + lane;
            int row = c >> 3;
            int col16 = (c & 7) ^ (row & 7);
            const ushort_t* ga = Kh + (size_t)(kv + row)*64 + col16*8;
            __builtin_amdgcn_global_load_lds((const __attribute__((address_space(1))) void*)ga,
                (__attribute__((address_space(3))) void*)(&Kb[bufi][(size_t)(is*256 + w*64)*8]), 16, 0, 0);
            const ushort_t* gv = Vh + (size_t)row*HW + kv + col16*8;
            __builtin_amdgcn_global_load_lds((const __attribute__((address_space(1))) void*)gv,
                (__attribute__((address_space(3))) void*)(&Vb[bufi][(size_t)(is*256 + w*64)*8]), 16, 0, 0);
        }
    };

    int cur = 0;
    stage(0, 0);
    __syncthreads();

    for (int t = 0; t < 16; ++t) {
        int kv = t * 64;
        if (t < 15) stage(cur ^ 1, kv + 64);
        int sw = l15 & 7;
        f32x4 s[4];
        #pragma unroll
        for (int st = 0; st < 4; ++st) {
            int krow = st*16 + l15;
            short8 bk0 = *(const short8*)&Kb[cur][(size_t)krow*64 + (size_t)((l4 ^ sw))*8];
            short8 bk1 = *(const short8*)&Kb[cur][(size_t)krow*64 + (size_t)(((4+l4) ^ sw))*8];
            f32x4 z = {};
            z = __builtin_amdgcn_mfma_f32_16x16x32_bf16(bk0, aq0, z, 0, 0, 0);
            z = __builtin_amdgcn_mfma_f32_16x16x32_bf16(bk1, aq1, z, 0, 0, 0);
            s[st] = z;
        }
        short8 va0[4], va1[4];
        #pragma unroll
        for (int dt = 0; dt < 4; ++dt) {
            int vrow = dt*16 + l15;
            va0[dt] = *(const short8*)&Vb[cur][(size_t)vrow*64 + (size_t)((l4 ^ sw))*8];
            va1[dt] = *(const short8*)&Vb[cur][(size_t)vrow*64 + (size_t)(((4+l4) ^ sw))*8];
        }
        int dr = qr - (kv >> 5);
        if (dr >= -1 && dr <= 2) {
            u64 tm = 0;
            if (dr <= 1) tm |= (u64)pat;
            if (dr >= 0) tm |= ((u64)pat) << 32;
            u64 sub = tm >> (l4*4);
            #pragma unroll
            for (int st = 0; st < 4; ++st)
                #pragma unroll
                for (int i = 0; i < 4; ++i)
                    if ((sub >> (st*16 + i)) & 1) s[st][i] = -1e30f;
        }
        float vmax = fmaxf(
            fmaxf(fmaxf(fmaxf(s[0][0], s[0][1]), fmaxf(s[0][2], s[0][3])),
                  fmaxf(fmaxf(s[1][0], s[1][1]), fmaxf(s[1][2], s[1][3]))),
            fmaxf(fmaxf(fmaxf(s[2][0], s[2][1]), fmaxf(s[2][2], s[2][3])),
                  fmaxf(fmaxf(s[3][0], s[3][1]), fmaxf(s[3][2], s[3][3]))));
        vmax = fmaxf(vmax, __shfl_xor(vmax, 16, 64));
        vmax = fmaxf(vmax, __shfl_xor(vmax, 32, 64));
        if (__any(vmax - m > 8.f)) {
            float mn = fmaxf(m, vmax);
            float sf = ex2(m - mn);
            lsum *= sf;
            #pragma unroll
            for (int dt = 0; dt < 4; ++dt)
                #pragma unroll
                for (int i = 0; i < 4; ++i) oacc[dt][i] *= sf;
            m = mn;
        }
        float ls = 0.f;
        #pragma unroll
        for (int st = 0; st < 4; ++st) {
            float p0 = ex2(s[st][0] - m), p1 = ex2(s[st][1] - m);
            float p2 = ex2(s[st][2] - m), p3 = ex2(s[st][3] - m);
            ls += (p0 + p1) + (p2 + p3);
            uint2 pk;
            pk.x = cvtpk(p0, p1);
            pk.y = cvtpk(p2, p3);
            *(uint2*)&P[w][l15][st*16 + l4*4] = pk;
        }
        ls += __shfl_xor(ls, 16, 64);
        ls += __shfl_xor(ls, 32, 64);
        lsum += ls;
        short8 pf0 = *(const short8*)&P[w][l15][l4*8];
        short8 pf1 = *(const short8*)&P[w][l15][32 + l4*8];
        #pragma unroll
        for (int dt = 0; dt < 4; ++dt) {
            oacc[dt] = __builtin_amdgcn_mfma_f32_16x16x32_bf16(va0[dt], pf0, oacc[dt], 0, 0, 0);
            oacc[dt] = __builtin_amdgcn_mfma_f32_16x16x32_bf16(va1[dt], pf1, oacc[dt], 0, 0, 0);
        }
        __syncthreads();
        cur ^= 1;
    }
    int b = bh / NHEAD, h = bh % NHEAD;
    float rl = 1.f / lsum;
    size_t obase = ((size_t)b*HW + q)*D_MODEL + h*64;
    #pragma unroll
    for (int dt = 0; dt < 4; ++dt) {
        uint2 pk;
        pk.x = cvtpk(oacc[dt][0]*rl, oacc[dt][1]*rl);
        pk.y = cvtpk(oacc[dt][2]*rl, oacc[dt][3]*rl);
        *(uint2*)&Ao[obase + dt*16 + l4*4] = pk;
    }
}

extern "C" void kernel_launch(void* const* d_in, const int* in_sizes, int n_in,
                              void* d_out, int out_size, void* d_ws, size_t ws_size,
                              hipStream_t stream) {
    const float* x      = (const float*)d_in[0];
    const float* w_qkv  = (const float*)d_in[1];
    const float* w_out  = (const float*)d_in[2];
    const float* gamma  = (const float*)d_in[3];
    float* out = (float*)d_out;

    char* ws = (char*)d_ws;
    size_t off = 0;
    auto alloc = [&](size_t bytes) { char* p = ws + off; off += (bytes + 255) & ~255ull; return p; };
    ushort_t* xn   = (ushort_t*)alloc((size_t)TOK*D_MODEL*2);
    ushort_t* wq   = (ushort_t*)alloc((size_t)QKV_N*D_MODEL*2);
    ushort_t* wo   = (ushort_t*)alloc((size_t)D_MODEL*D_MODEL*2);
    float* sint    = (float*)alloc((size_t)HW*32*4);
    float* cost    = (float*)alloc((size_t)HW*32*4);
    ushort_t* Qr   = (ushort_t*)alloc((size_t)BH*HW*HD*2);
    ushort_t* Kr   = (ushort_t*)alloc((size_t)BH*HW*HD*2);
    ushort_t* VTt  = (ushort_t*)alloc((size_t)BH*HD*HW*2);
    ushort_t* Ao   = (ushort_t*)alloc((size_t)TOK*D_MODEL*2);

    rmsnorm_kernel<<<TOK/4, 256, 0, stream>>>(x, gamma, xn);
    cvt_kernel<<<(QKV_N*D_MODEL + 255)/256, 256, 0, stream>>>(w_qkv, wq, QKV_N*D_MODEL);
    cvt_kernel<<<(D_MODEL*D_MODEL + 255)/256, 256, 0, stream>>>(w_out, wo, D_MODEL*D_MODEL);
    sincos_kernel<<<HW*32/256, 256, 0, stream>>>(sint, cost);
    gemm64<36,0><<<2304, 64, 0, stream>>>(xn, wq, sint, cost, Qr, Kr, VTt, nullptr);
    attn_kernel<<<768, 256, 0, stream>>>(Qr, Kr, VTt, Ao);
    gemm64<12,1><<<768, 64, 0, stream>>>(Ao, wo, nullptr, nullptr, nullptr, nullptr, nullptr, out);
}